// Round 9
// baseline (825.728 us; speedup 1.0000x reference)
//
#include <hip/hip_runtime.h>
#include <hip/hip_bf16.h>
#include <math.h>

typedef __hip_bfloat16 bf16;
typedef __attribute__((ext_vector_type(8))) short short8;     // 8 x bf16 MFMA frag
typedef __attribute__((ext_vector_type(16))) float floatx16;  // 32x32 acc

// Problem constants: B=64, DIM=256, HID=512, NH=4, KD=16, D=64, 28x28, WH=7
#define BB    64
#define DIMC  256
#define HIDC  512
#define NHH   4
#define HH_   28
#define WW_   28
#define PP    784   // 28*28

__device__ __forceinline__ float toF(bf16 x) { return __bfloat162float(x); }
__device__ __forceinline__ unsigned short f2bits(float f) {
    union { bf16 h; unsigned short u; } cv; cv.h = __float2bfloat16(f); return cv.u;
}
__device__ __forceinline__ float bits2f(unsigned short u) {
    union { unsigned int u32; float f; } cv; cv.u32 = ((unsigned int)u) << 16; return cv.f;
}

// ---------------------------------------------------------------------------
// fp32 -> bf16 weight convert
// ---------------------------------------------------------------------------
__global__ __launch_bounds__(256) void cvt_f2b(
    const float* __restrict__ s, bf16* __restrict__ d, int n)
{
    int i = blockIdx.x * 256 + threadIdx.x;
    if (i < n) d[i] = __float2bfloat16(s[i]);
}

// ---------------------------------------------------------------------------
// fp32 NCHW [64][256][784] -> bf16 NHWC [64][784][256] (LDS 32x32 transpose)
// grid (25, 8, 64), block 256
// ---------------------------------------------------------------------------
__global__ __launch_bounds__(256) void tr_cvt(
    const float* __restrict__ in, bf16* __restrict__ out)
{
    __shared__ float t[32][33];
    int n  = blockIdx.z;
    int p0 = blockIdx.x * 32;
    int c0 = blockIdx.y * 32;
    int tx = threadIdx.x & 31;
    int ty = threadIdx.x >> 5;   // 0..7
#pragma unroll
    for (int e = 0; e < 4; e++) {
        int c = c0 + ty + e * 8;
        int p = p0 + tx;
        if (p < PP) t[ty + e * 8][tx] = in[((size_t)n * DIMC + c) * PP + p];
    }
    __syncthreads();
#pragma unroll
    for (int e = 0; e < 4; e++) {
        int p = p0 + ty + e * 8;
        int c = c0 + tx;
        if (p < PP) out[((size_t)n * PP + p) * DIMC + c] = __float2bfloat16(t[tx][ty + e * 8]);
    }
}

// ---------------------------------------------------------------------------
// Depthwise 3x3 conv + BN + residual (NCHW fp32) — proven (round 3)
// ---------------------------------------------------------------------------
__global__ __launch_bounds__(256) void dw3x3_kernel(
    const float* __restrict__ in, const float* __restrict__ w,
    const float* __restrict__ s, const float* __restrict__ b,
    float* __restrict__ out)
{
    int nc = blockIdx.x;
    int c  = nc & (DIMC - 1);
    const float* ip = in + (size_t)nc * PP;
    float*       op = out + (size_t)nc * PP;
    float w9[9];
#pragma unroll
    for (int i = 0; i < 9; i++) w9[i] = w[c * 9 + i];
    float sc = s[c], bb = b[c];
    for (int p = threadIdx.x; p < PP; p += 256) {
        int h = p / WW_, x = p % WW_;
        float acc = 0.f;
#pragma unroll
        for (int i = 0; i < 3; i++) {
            int hh = h + i - 1;
            if (hh < 0 || hh >= HH_) continue;
#pragma unroll
            for (int j = 0; j < 3; j++) {
                int xx = x + j - 1;
                if (xx < 0 || xx >= WW_) continue;
                acc += w9[i * 3 + j] * ip[hh * WW_ + xx];
            }
        }
        op[p] = ip[p] + acc * sc + bb;
    }
}

// ---------------------------------------------------------------------------
// Per-head depthwise 5x5 + BN on q channels, NHWC bf16 in/out. (proven r8)
// ---------------------------------------------------------------------------
__global__ __launch_bounds__(256) void dws5x5_nhwc(
    const bf16* __restrict__ qkv,   // [64][784][384]
    const float* __restrict__ w,    // [64][25]  (hk-major)
    const float* __restrict__ s, const float* __restrict__ b,
    bf16* __restrict__ qout)        // [64][784][64]
{
    int n  = blockIdx.y;
    int p  = blockIdx.x * 4 + (threadIdx.x >> 6);
    int hk = threadIdx.x & 63;
    int hh = hk >> 4, kc = hk & 15;
    int cin = hh * 96 + kc;
    int h = p / 28, x = p % 28;
    float w25[25];
#pragma unroll
    for (int i = 0; i < 25; i++) w25[i] = w[hk * 25 + i];
    float acc = 0.f;
#pragma unroll
    for (int i = 0; i < 5; i++) {
        int h2 = h + i - 2;
        if (h2 < 0 || h2 >= HH_) continue;
#pragma unroll
        for (int j = 0; j < 5; j++) {
            int x2 = x + j - 2;
            if (x2 < 0 || x2 >= WW_) continue;
            acc += w25[i * 5 + j] * toF(qkv[((size_t)n * PP + h2 * 28 + x2) * 384 + cin]);
        }
    }
    qout[((size_t)n * PP + p) * 64 + hk] = __float2bfloat16(acc * s[hk] + b[hk]);
}

// ---------------------------------------------------------------------------
// 1x1 conv as bf16 MFMA GEMM, 32x32x16 shape, tile 128(co) x 128(p).
//   out[n,co,p] = sum_ci W[co,ci] * X[n,p,ci]   (X is NHWC bf16)
// Block 256 = 4 waves: wave (wco, wp) owns co 64-half x p 64-half =
// 2x2 tiles of 32x32 -> acc[2][2] floatx16. Per K-32 step per wave:
// 4 A-frags (global, L1/L2-hot), 4 B-ds_read_b128, 8 MFMA (32k FLOP each)
// -> MFMA-bound (LDS 192 cyc vs MFMA 258 cyc per CU-step).
// Fragment layouts (HW-verified m74/m101 family):
//   A[m=lane&31][k=(lane>>5)*8+j], B[k=(lane>>5)*8+j][n=lane&31],
//   D: col=lane&31, row=(reg&3)+8*(reg>>2)+4*(lane>>5).
// OUTMODE: 0 = bf16 NHWC; 1 = fp32 NCHW; 2 = both.  grid (7, M/128, 64)
// ---------------------------------------------------------------------------
template <bool RELU, bool RES, int OUTMODE>
__global__ __launch_bounds__(256) void gemm_mfma(
    const bf16* __restrict__ Wb,    // [M][K] bf16
    const bf16* __restrict__ X,     // [64][784][K] bf16 NHWC
    const float* __restrict__ S, const float* __restrict__ Bb,
    const float* __restrict__ res,  // [64][M][784] fp32 NCHW (if RES)
    float* __restrict__ outF,       // fp32 NCHW (OUTMODE 1/2)
    bf16*  __restrict__ outB,       // bf16 NHWC (OUTMODE 0/2)
    int M, int K)
{
    int n    = blockIdx.z;
    int co0  = blockIdx.y * 128;
    int p0   = blockIdx.x * 128;    // 7*128=896 >= 784: bounds-checked
    int tid  = threadIdx.x;
    int wv   = tid >> 6;
    int wco  = wv >> 1;             // 0..1 : co 64-half
    int wp   = wv & 1;              // 0..1 : p  64-half
    int lane = tid & 63;
    int l31  = lane & 31;
    int l5   = lane >> 5;

    __shared__ __align__(16) unsigned short Blds[128 * 40];  // [pp][kk] pitch 40

    floatx16 acc[2][2];
#pragma unroll
    for (int a = 0; a < 2; a++)
#pragma unroll
        for (int b = 0; b < 2; b++)
#pragma unroll
            for (int i = 0; i < 16; i++) acc[a][b][i] = 0.f;

    const unsigned short* Xb = (const unsigned short*)X + ((size_t)n * PP + p0) * K;
    const unsigned short* Wu = (const unsigned short*)Wb;

    // staging: 512 tasks = 128 pp x 4 granules of 8k; thread does tid, tid+256
    int pp_a = tid >> 1;                       // wrong split would break; use >>2:
    pp_a = tid >> 2;  int G_a = tid & 3;       // pp 0..63
    int pp_b = (tid + 256) >> 2, G_b = tid & 3; // pp 64..127, same G pattern

    // per-wave A row base (two 32-co tiles)
    const unsigned short* Arow0 = Wu + (size_t)(co0 + wco * 64 + l31) * K + l5 * 8;
    const unsigned short* Arow1 = Arow0 + (size_t)32 * K;

    for (int k0 = 0; k0 < K; k0 += 32) {
        // ---- stage B tile: 128p x 32k ----
        {
            int p = p0 + pp_a;
            uint4 v = make_uint4(0, 0, 0, 0);
            if (p < PP) v = *(const uint4*)(Xb + (size_t)pp_a * K + k0 + G_a * 8);
            *(uint4*)&Blds[pp_a * 40 + G_a * 8] = v;
        }
        {
            int p = p0 + pp_b;
            uint4 v = make_uint4(0, 0, 0, 0);
            if (p < PP) v = *(const uint4*)(Xb + (size_t)pp_b * K + k0 + G_b * 8);
            *(uint4*)&Blds[pp_b * 40 + G_b * 8] = v;
        }
        // ---- A fragments (global; weights are L1/L2-hot) ----
        short8 afr[2][2];   // [ct][kh]
#pragma unroll
        for (int kh = 0; kh < 2; kh++) {
            afr[0][kh] = *(const short8*)(Arow0 + k0 + kh * 16);
            afr[1][kh] = *(const short8*)(Arow1 + k0 + kh * 16);
        }
        __syncthreads();
        // ---- B fragments + MFMA ----
#pragma unroll
        for (int pt = 0; pt < 2; pt++) {
#pragma unroll
            for (int kh = 0; kh < 2; kh++) {
                short8 bfr = *(const short8*)&Blds[(wp * 64 + pt * 32 + l31) * 40 + kh * 16 + l5 * 8];
                acc[0][pt] = __builtin_amdgcn_mfma_f32_32x32x16_bf16(afr[0][kh], bfr, acc[0][pt], 0, 0, 0);
                acc[1][pt] = __builtin_amdgcn_mfma_f32_32x32x16_bf16(afr[1][kh], bfr, acc[1][pt], 0, 0, 0);
            }
        }
        __syncthreads();
    }

    // ---- epilogue ----
#pragma unroll
    for (int ct = 0; ct < 2; ct++) {
#pragma unroll
        for (int pt = 0; pt < 2; pt++) {
            int p = p0 + wp * 64 + pt * 32 + l31;
            if (p >= PP) continue;
#pragma unroll
            for (int g = 0; g < 4; g++) {
                int cob = co0 + wco * 64 + ct * 32 + g * 8 + l5 * 4;  // 4 consecutive co
                float y[4];
#pragma unroll
                for (int r = 0; r < 4; r++) {
                    y[r] = acc[ct][pt][g * 4 + r] * S[cob + r] + Bb[cob + r];
                    if (RELU) y[r] = fmaxf(y[r], 0.f);
                    if (RES) y[r] += res[((size_t)n * M + cob + r) * PP + p];
                }
                if (OUTMODE == 1 || OUTMODE == 2) {
#pragma unroll
                    for (int r = 0; r < 4; r++)
                        outF[((size_t)n * M + cob + r) * PP + p] = y[r];
                }
                if (OUTMODE == 0 || OUTMODE == 2) {
                    union { unsigned short h4[4]; uint2 u; } pk;
#pragma unroll
                    for (int r = 0; r < 4; r++) pk.h4[r] = f2bits(y[r]);
                    *(uint2*)((unsigned short*)outB + ((size_t)n * PP + p) * M + cob) = pk.u;
                }
            }
        }
    }
}

// ---------------------------------------------------------------------------
// 7x7 window attention, NHWC bf16 I/O ---- unchanged from round 8 (proven).
// ---------------------------------------------------------------------------
__global__ __launch_bounds__(256) void attn_kernel(
    const bf16*  __restrict__ Q,       // [64][784][64] NHWC (hk = hh*16+kc)
    const bf16*  __restrict__ KV,      // [64][784][384] NHWC
    const float* __restrict__ pos,     // [4][49][49]
    bf16* __restrict__ O)              // [64][784][256] NHWC (c = hh*64+d)
{
    int wjp = blockIdx.x & 1, wi = blockIdx.x >> 1;
    int hh  = blockIdx.y, n = blockIdx.z;
    int tid = threadIdx.x;
    int pbase = wi * 7 * 28 + wjp * 14;

    __shared__ __align__(16) unsigned short qL[16 * 98];   // [kc][lp]
    __shared__ __align__(16) unsigned short kL[16 * 98];
    __shared__ __align__(16) unsigned short vL[98 * 66];   // [lp][d] pitch 66
    __shared__ float sL[98 * 51];                          // [w*49+qi][ki] pitch 51

    const unsigned short* KVu = (const unsigned short*)KV;
    const unsigned short* Qu  = (const unsigned short*)Q;

    for (int idx = tid; idx < 1568; idx += 256) {
        int lp = idx >> 4, kc = idx & 15;
        int p  = pbase + (lp / 14) * 28 + lp % 14;
        qL[kc * 98 + lp] = Qu[((size_t)n * PP + p) * 64 + hh * 16 + kc];
        kL[kc * 98 + lp] = KVu[((size_t)n * PP + p) * 384 + hh * 96 + 16 + kc];
    }
    for (int idx = tid; idx < 6272; idx += 256) {
        int lp = idx >> 6, d = idx & 63;
        int p = pbase + (lp / 14) * 28 + lp % 14;
        vL[lp * 66 + d] = KVu[((size_t)n * PP + p) * 384 + hh * 96 + 32 + d];
    }
    __syncthreads();

    for (int idx = tid; idx < 4802; idx += 256) {
        int w  = idx / 2401;
        int rm = idx - w * 2401;
        int qi = rm / 49, ki = rm - qi * 49;
        int lpq = (qi / 7) * 14 + w * 7 + qi % 7;
        int lpk = (ki / 7) * 14 + w * 7 + ki % 7;
        float acc = 0.f;
#pragma unroll
        for (int kc = 0; kc < 16; kc++)
            acc += bits2f(qL[kc * 98 + lpq]) * bits2f(kL[kc * 98 + lpk]);
        sL[(w * 49 + qi) * 51 + ki] = acc * 0.25f + pos[(hh * 49 + qi) * 49 + ki];
    }
    __syncthreads();

    if (tid < 98) {
        float* row = &sL[tid * 51];
        float m = row[0];
        for (int ki = 1; ki < 49; ki++) m = fmaxf(m, row[ki]);
        float sum = 0.f;
        for (int ki = 0; ki < 49; ki++) {
            float e = __expf(row[ki] - m);
            row[ki] = e;
            sum += e;
        }
        float inv = 1.f / sum;
        for (int ki = 0; ki < 49; ki++) row[ki] *= inv;
    }
    __syncthreads();

    unsigned short* Ou = (unsigned short*)O;
    for (int idx = tid; idx < 3136; idx += 256) {
        int lp = idx >> 5, d2 = idx & 31;
        int r = lp / 14, c = lp % 14;
        int w = c / 7, cc = c - w * 7;
        int qi = r * 7 + cc;
        const float* srow = &sL[(w * 49 + qi) * 51];
        float a0 = 0.f, a1 = 0.f;
#pragma unroll
        for (int ki = 0; ki < 49; ki++) {
            int lpk = (ki / 7) * 14 + w * 7 + ki % 7;
            unsigned int v2 = *(const unsigned int*)&vL[lpk * 66 + d2 * 2];
            float sv = srow[ki];
            a0 += sv * bits2f((unsigned short)(v2 & 0xFFFF));
            a1 += sv * bits2f((unsigned short)(v2 >> 16));
        }
        int p = pbase + r * 28 + c;
        unsigned int o2 = (unsigned int)f2bits(fmaxf(a0, 0.f))
                        | ((unsigned int)f2bits(fmaxf(a1, 0.f)) << 16);
        *(unsigned int*)&Ou[((size_t)n * PP + p) * 256 + hh * 64 + d2 * 2] = o2;
    }
}

// ---------------------------------------------------------------------------
extern "C" void kernel_launch(void* const* d_in, const int* in_sizes, int n_in,
                              void* d_out, int out_size, void* d_ws, size_t ws_size,
                              hipStream_t stream)
{
    const float* x0     = (const float*)d_in[0];
    const float* dw0_w  = (const float*)d_in[1];
    const float* dw0_s  = (const float*)d_in[2];
    const float* dw0_b  = (const float*)d_in[3];
    const float* dw1_w  = (const float*)d_in[4];
    const float* dw1_s  = (const float*)d_in[5];
    const float* dw1_b  = (const float*)d_in[6];
    const float* f0w1   = (const float*)d_in[7];
    const float* f0s1   = (const float*)d_in[8];
    const float* f0b1   = (const float*)d_in[9];
    const float* f0w2   = (const float*)d_in[10];
    const float* f0s2   = (const float*)d_in[11];
    const float* f0b2   = (const float*)d_in[12];
    const float* f1w1   = (const float*)d_in[13];
    const float* f1s1   = (const float*)d_in[14];
    const float* f1b1   = (const float*)d_in[15];
    const float* f1w2   = (const float*)d_in[16];
    const float* f1s2   = (const float*)d_in[17];
    const float* f1b2   = (const float*)d_in[18];
    const float* qkv_w  = (const float*)d_in[19];
    const float* qkv_s  = (const float*)d_in[20];
    const float* qkv_b  = (const float*)d_in[21];
    const float* dws_w  = (const float*)d_in[22];
    const float* dws_s  = (const float*)d_in[23];
    const float* dws_b  = (const float*)d_in[24];
    const float* proj_w = (const float*)d_in[25];
    const float* proj_s = (const float*)d_in[26];
    const float* proj_b = (const float*)d_in[27];
    const float* pos    = (const float*)d_in[28];

    // -------- workspace (aliased, same proven r8 scheme) --------
    const size_t NXB = (size_t)BB * DIMC * PP * 4;    // 51,380,224 B
    char* base  = (char*)d_ws;
    float* X1   = (float*)base;
    bf16*  Hb   = (bf16*)(base + NXB);
    bf16*  Qb   = Hb;                                  // alias, disjoint in time
    char*  C_   = base + 2 * NXB;
    bf16*  QKVb = (bf16*)C_;
    float* X2   = (float*)C_;                          // alias, disjoint in time
    bf16*  X1b  = (bf16*)(base + 3 * NXB);             // 25.7 MB
    bf16*  Wc   = (bf16*)(base + 3 * NXB + NXB / 2);
    bf16*  Ob   = (bf16*)d_out;
    float* outp = (float*)d_out;

    bf16* Wf0w1 = Wc;                  // [512][256]
    bf16* Wf0w2 = Wf0w1 + 131072;      // [256][512]
    bf16* Wf1w1 = Wf0w2 + 131072;      // [512][256]
    bf16* Wf1w2 = Wf1w1 + 131072;      // [256][512]
    bf16* Wqkv  = Wf1w2 + 131072;      // [384][256]
    bf16* Wproj = Wqkv + 98304;        // [256][256]

    dim3 blk(256);

    // 0) weights fp32 -> bf16
    cvt_f2b<<<512, blk, 0, stream>>>(f0w1, Wf0w1, 131072);
    cvt_f2b<<<512, blk, 0, stream>>>(f0w2, Wf0w2, 131072);
    cvt_f2b<<<512, blk, 0, stream>>>(f1w1, Wf1w1, 131072);
    cvt_f2b<<<512, blk, 0, stream>>>(f1w2, Wf1w2, 131072);
    cvt_f2b<<<384, blk, 0, stream>>>(qkv_w, Wqkv, 98304);
    cvt_f2b<<<256, blk, 0, stream>>>(proj_w, Wproj, 65536);

    // 1) x = x + dw0(x); mirror to NHWC bf16
    dw3x3_kernel<<<BB * DIMC, blk, 0, stream>>>(x0, dw0_w, dw0_s, dw0_b, X1);
    tr_cvt<<<dim3(25, 8, BB), blk, 0, stream>>>(X1, X1b);

    // 2-3) ffn0 (second GEMM refreshes both X1 fp32 and X1b NHWC)
    gemm_mfma<true, false, 0><<<dim3(7, HIDC / 128, BB), blk, 0, stream>>>(
        Wf0w1, X1b, f0s1, f0b1, nullptr, nullptr, Hb, HIDC, DIMC);
    gemm_mfma<false, true, 2><<<dim3(7, DIMC / 128, BB), blk, 0, stream>>>(
        Wf0w2, Hb, f0s2, f0b2, X1, X1, X1b, DIMC, HIDC);

    // 4-7) attention
    gemm_mfma<false, false, 0><<<dim3(7, 384 / 128, BB), blk, 0, stream>>>(
        Wqkv, X1b, qkv_s, qkv_b, nullptr, nullptr, QKVb, 384, DIMC);
    dws5x5_nhwc<<<dim3(196, BB), blk, 0, stream>>>(QKVb, dws_w, dws_s, dws_b, Qb);
    attn_kernel<<<dim3(8, NHH, BB), blk, 0, stream>>>(Qb, QKVb, pos, Ob);
    gemm_mfma<false, true, 1><<<dim3(7, DIMC / 128, BB), blk, 0, stream>>>(
        Wproj, Ob, proj_s, proj_b, X1, X1, nullptr, DIMC, DIMC);

    // 8) x = x + dw1(x)  (QKVb dead -> X2); mirror to NHWC bf16 (reuse X1b)
    dw3x3_kernel<<<BB * DIMC, blk, 0, stream>>>(X1, dw1_w, dw1_s, dw1_b, X2);
    tr_cvt<<<dim3(25, 8, BB), blk, 0, stream>>>(X2, X1b);

    // 9-10) ffn1, final fp32 NCHW to d_out
    gemm_mfma<true, false, 0><<<dim3(7, HIDC / 128, BB), blk, 0, stream>>>(
        Wf1w1, X1b, f1s1, f1b1, nullptr, nullptr, Hb, HIDC, DIMC);
    gemm_mfma<false, true, 1><<<dim3(7, DIMC / 128, BB), blk, 0, stream>>>(
        Wf1w2, Hb, f1s2, f1b2, X2, outp, nullptr, DIMC, HIDC);
}

// Round 10
// 774.696 us; speedup vs baseline: 1.0659x; 1.0659x over previous
//
#include <hip/hip_runtime.h>
#include <hip/hip_bf16.h>
#include <math.h>

typedef __hip_bfloat16 bf16;
typedef __attribute__((ext_vector_type(8))) short short8;   // 8 x bf16 MFMA frag
typedef __attribute__((ext_vector_type(4))) float floatx4;  // 4 x f32 MFMA acc

// Problem constants: B=64, DIM=256, HID=512, NH=4, KD=16, D=64, 28x28, WH=7
#define BB    64
#define DIMC  256
#define HIDC  512
#define NHH   4
#define HH_   28
#define WW_   28
#define PP    784   // 28*28

__device__ __forceinline__ float toF(bf16 x) { return __bfloat162float(x); }
__device__ __forceinline__ unsigned short f2bits(float f) {
    union { bf16 h; unsigned short u; } cv; cv.h = __float2bfloat16(f); return cv.u;
}
__device__ __forceinline__ float bits2f(unsigned short u) {
    union { unsigned int u32; float f; } cv; cv.u32 = ((unsigned int)u) << 16; return cv.f;
}

// ---------------------------------------------------------------------------
// fp32 -> bf16 weight convert
// ---------------------------------------------------------------------------
__global__ __launch_bounds__(256) void cvt_f2b(
    const float* __restrict__ s, bf16* __restrict__ d, int n)
{
    int i = blockIdx.x * 256 + threadIdx.x;
    if (i < n) d[i] = __float2bfloat16(s[i]);
}

// ---------------------------------------------------------------------------
// fp32 NCHW [64][256][784] -> bf16 NHWC [64][784][256] (LDS 32x32 transpose)
// grid (25, 8, 64), block 256
// ---------------------------------------------------------------------------
__global__ __launch_bounds__(256) void tr_cvt(
    const float* __restrict__ in, bf16* __restrict__ out)
{
    __shared__ float t[32][33];
    int n  = blockIdx.z;
    int p0 = blockIdx.x * 32;
    int c0 = blockIdx.y * 32;
    int tx = threadIdx.x & 31;
    int ty = threadIdx.x >> 5;   // 0..7
#pragma unroll
    for (int e = 0; e < 4; e++) {
        int c = c0 + ty + e * 8;
        int p = p0 + tx;
        if (p < PP) t[ty + e * 8][tx] = in[((size_t)n * DIMC + c) * PP + p];
    }
    __syncthreads();
#pragma unroll
    for (int e = 0; e < 4; e++) {
        int p = p0 + ty + e * 8;
        int c = c0 + tx;
        if (p < PP) out[((size_t)n * PP + p) * DIMC + c] = __float2bfloat16(t[tx][ty + e * 8]);
    }
}

// ---------------------------------------------------------------------------
// Depthwise 3x3 conv + BN + residual (NCHW fp32) — proven (round 3)
// ---------------------------------------------------------------------------
__global__ __launch_bounds__(256) void dw3x3_kernel(
    const float* __restrict__ in, const float* __restrict__ w,
    const float* __restrict__ s, const float* __restrict__ b,
    float* __restrict__ out)
{
    int nc = blockIdx.x;
    int c  = nc & (DIMC - 1);
    const float* ip = in + (size_t)nc * PP;
    float*       op = out + (size_t)nc * PP;
    float w9[9];
#pragma unroll
    for (int i = 0; i < 9; i++) w9[i] = w[c * 9 + i];
    float sc = s[c], bb = b[c];
    for (int p = threadIdx.x; p < PP; p += 256) {
        int h = p / WW_, x = p % WW_;
        float acc = 0.f;
#pragma unroll
        for (int i = 0; i < 3; i++) {
            int hh = h + i - 1;
            if (hh < 0 || hh >= HH_) continue;
#pragma unroll
            for (int j = 0; j < 3; j++) {
                int xx = x + j - 1;
                if (xx < 0 || xx >= WW_) continue;
                acc += w9[i * 3 + j] * ip[hh * WW_ + xx];
            }
        }
        op[p] = ip[p] + acc * sc + bb;
    }
}

// ---------------------------------------------------------------------------
// Per-head depthwise 5x5 + BN on q channels, NHWC bf16 in/out. (proven r8)
// ---------------------------------------------------------------------------
__global__ __launch_bounds__(256) void dws5x5_nhwc(
    const bf16* __restrict__ qkv,   // [64][784][384]
    const float* __restrict__ w,    // [64][25]  (hk-major)
    const float* __restrict__ s, const float* __restrict__ b,
    bf16* __restrict__ qout)        // [64][784][64]
{
    int n  = blockIdx.y;
    int p  = blockIdx.x * 4 + (threadIdx.x >> 6);
    int hk = threadIdx.x & 63;
    int hh = hk >> 4, kc = hk & 15;
    int cin = hh * 96 + kc;
    int h = p / 28, x = p % 28;
    float w25[25];
#pragma unroll
    for (int i = 0; i < 25; i++) w25[i] = w[hk * 25 + i];
    float acc = 0.f;
#pragma unroll
    for (int i = 0; i < 5; i++) {
        int h2 = h + i - 2;
        if (h2 < 0 || h2 >= HH_) continue;
#pragma unroll
        for (int j = 0; j < 5; j++) {
            int x2 = x + j - 2;
            if (x2 < 0 || x2 >= WW_) continue;
            acc += w25[i * 5 + j] * toF(qkv[((size_t)n * PP + h2 * 28 + x2) * 384 + cin]);
        }
    }
    qout[((size_t)n * PP + p) * 64 + hk] = __float2bfloat16(acc * s[hk] + b[hk]);
}

// ---------------------------------------------------------------------------
// 1x1 conv as bf16 MFMA GEMM — EXACT r8 version (proven at 791 us total).
// Tile 64(co) x 112(p), K-step 32, 4 waves; uint4 staging, pitch-40 LDS.
// OUTMODE: 0 = bf16 NHWC; 1 = fp32 NCHW; 2 = both.   grid (7, M/64, 64)
// ---------------------------------------------------------------------------
template <bool RELU, bool RES, int OUTMODE>
__global__ __launch_bounds__(256) void gemm_mfma(
    const bf16* __restrict__ Wb,    // [M][K] bf16
    const bf16* __restrict__ X,     // [64][784][K] bf16 NHWC
    const float* __restrict__ S, const float* __restrict__ Bb,
    const float* __restrict__ res,  // [64][M][784] fp32 NCHW (if RES)
    float* __restrict__ outF,       // fp32 NCHW (OUTMODE 1/2)
    bf16*  __restrict__ outB,       // bf16 NHWC (OUTMODE 0/2)
    int M, int K)
{
    int n    = blockIdx.z;
    int co0  = blockIdx.y * 64;
    int p0   = blockIdx.x * 112;
    int tid  = threadIdx.x;
    int wv   = tid >> 6;
    int ln   = tid & 63;
    int l15  = ln & 15;
    int quad = ln >> 4;

    __shared__ __align__(16) unsigned short Blds[112 * 40];  // [pp][kk], pitch 40

    floatx4 acc[7];
#pragma unroll
    for (int t = 0; t < 7; t++) acc[t] = (floatx4){0.f, 0.f, 0.f, 0.f};

    const bf16* Arow = Wb + (size_t)(co0 + wv * 16 + l15) * K + quad * 8;
    const unsigned short* Xb = (const unsigned short*)X + ((size_t)n * PP + p0) * K;

    int pp_a = tid >> 2, G_a = tid & 3;                 // pp_a in [0,64)
    int idx_b = tid + 256;
    int pp_b = idx_b >> 2, G_b = idx_b & 3;             // pp_b in [64,128), valid < 112

    for (int k0 = 0; k0 < K; k0 += 32) {
        {
            uint4 v = *(const uint4*)(Xb + (size_t)pp_a * K + k0 + G_a * 8);
            *(uint4*)&Blds[pp_a * 40 + G_a * 8] = v;
        }
        if (idx_b < 448) {
            uint4 v = *(const uint4*)(Xb + (size_t)pp_b * K + k0 + G_b * 8);
            *(uint4*)&Blds[pp_b * 40 + G_b * 8] = v;
        }
        short8 afrag = *(const short8*)(Arow + k0);
        __syncthreads();
#pragma unroll
        for (int t = 0; t < 7; t++) {
            short8 bfrag = *(const short8*)&Blds[(t * 16 + l15) * 40 + quad * 8];
            acc[t] = __builtin_amdgcn_mfma_f32_16x16x32_bf16(afrag, bfrag, acc[t], 0, 0, 0);
        }
        __syncthreads();
    }

    int cobase = co0 + wv * 16 + quad * 4;
    float s4[4], b4[4];
#pragma unroll
    for (int r = 0; r < 4; r++) { s4[r] = S[cobase + r]; b4[r] = Bb[cobase + r]; }

#pragma unroll
    for (int t = 0; t < 7; t++) {
        int p = p0 + t * 16 + l15;   // always < 784
        float y[4];
#pragma unroll
        for (int r = 0; r < 4; r++) {
            y[r] = acc[t][r] * s4[r] + b4[r];
            if (RELU) y[r] = fmaxf(y[r], 0.f);
            if (RES) y[r] += res[((size_t)n * M + cobase + r) * PP + p];
        }
        if (OUTMODE == 1 || OUTMODE == 2) {
#pragma unroll
            for (int r = 0; r < 4; r++)
                outF[((size_t)n * M + cobase + r) * PP + p] = y[r];
        }
        if (OUTMODE == 0 || OUTMODE == 2) {
            union { unsigned short h4[4]; uint2 u; } pk;
#pragma unroll
            for (int r = 0; r < 4; r++) pk.h4[r] = f2bits(y[r]);
            *(uint2*)((unsigned short*)outB + ((size_t)n * PP + p) * M + cobase) = pk.u;
        }
    }
}

// ---------------------------------------------------------------------------
// 7x7 window attention, NHWC bf16 I/O. Block per (n, head, win-row, col-pair).
// grid (8, 4, 64). Covers 2 windows: lp = r*14 + c, global p = pbase+r*28+c.
// ROUND-10 CHANGE (LDS-throughput fix): register-blocked inner loops.
//  - q/k in LDS as [lp][kc] pitch 18 (bank stride 9, coprime 32); S loop reads
//    packed u32 (2 kc per read): 16 LDS reads per S entry instead of 32.
//  - v in LDS pitch 64 u16; PV thread owns (lp, 8 channels): per ki ONE
//    ds_read_b128 (8 ch) + one b32 srow read feeds 16 FLOP (was 2 reads/4 FLOP).
//  - sL pitch 50 (2-way bank aliasing = free). LDS total 39.1 KB -> 4 blocks/CU.
// ---------------------------------------------------------------------------
__global__ __launch_bounds__(256) void attn_kernel(
    const bf16*  __restrict__ Q,       // [64][784][64] NHWC (hk = hh*16+kc)
    const bf16*  __restrict__ KV,      // [64][784][384] NHWC
    const float* __restrict__ pos,     // [4][49][49]
    bf16* __restrict__ O)              // [64][784][256] NHWC (c = hh*64+d)
{
    int wjp = blockIdx.x & 1, wi = blockIdx.x >> 1;
    int hh  = blockIdx.y, n = blockIdx.z;
    int tid = threadIdx.x;
    int pbase = wi * 7 * 28 + wjp * 14;

    __shared__ __align__(16) unsigned short qL[98 * 18];   // [lp][kc] pitch 18
    __shared__ __align__(16) unsigned short kL[98 * 18];
    __shared__ __align__(16) unsigned short vL[98 * 64];   // [lp][d] pitch 64
    __shared__ float sL[98 * 50];                          // [w*49+qi][ki] pitch 50

    const unsigned short* KVu = (const unsigned short*)KV;
    const unsigned short* Qu  = (const unsigned short*)Q;

    // ---- load q, k as u32 pairs: 784 tasks = 98 lp x 8 kc-pairs ----
    for (int idx = tid; idx < 784; idx += 256) {
        int lp = idx >> 3, e = idx & 7;
        int p  = pbase + (lp / 14) * 28 + lp % 14;
        unsigned int qv = *(const unsigned int*)&Qu[((size_t)n * PP + p) * 64 + hh * 16 + e * 2];
        unsigned int kv = *(const unsigned int*)&KVu[((size_t)n * PP + p) * 384 + hh * 96 + 16 + e * 2];
        *(unsigned int*)&qL[lp * 18 + e * 2] = qv;
        *(unsigned int*)&kL[lp * 18 + e * 2] = kv;
    }
    // ---- load v as u32 pairs: 3136 tasks = 98 lp x 32 ch-pairs ----
    for (int idx = tid; idx < 3136; idx += 256) {
        int lp = idx >> 5, d2 = idx & 31;
        int p = pbase + (lp / 14) * 28 + lp % 14;
        unsigned int vv = *(const unsigned int*)&KVu[((size_t)n * PP + p) * 384 + hh * 96 + 32 + d2 * 2];
        *(unsigned int*)&vL[lp * 64 + d2 * 2] = vv;
    }
    __syncthreads();

    // ---- S = 0.25*q.k + pos  (2 windows x 49 x 49) ----
    for (int idx = tid; idx < 4802; idx += 256) {
        int w  = idx / 2401;
        int rm = idx - w * 2401;
        int qi = rm / 49, ki = rm - qi * 49;
        int lpq = (qi / 7) * 14 + w * 7 + qi % 7;
        int lpk = (ki / 7) * 14 + w * 7 + ki % 7;
        float acc = 0.f;
#pragma unroll
        for (int e = 0; e < 8; e++) {
            unsigned int qw = *(const unsigned int*)&qL[lpq * 18 + e * 2];
            unsigned int kw = *(const unsigned int*)&kL[lpk * 18 + e * 2];
            acc += bits2f((unsigned short)(qw & 0xFFFF)) * bits2f((unsigned short)(kw & 0xFFFF));
            acc += bits2f((unsigned short)(qw >> 16))    * bits2f((unsigned short)(kw >> 16));
        }
        sL[(w * 49 + qi) * 50 + ki] = acc * 0.25f + pos[(hh * 49 + qi) * 49 + ki];
    }
    __syncthreads();

    // ---- softmax (one thread per row; 98 rows) ----
    if (tid < 98) {
        float* row = &sL[tid * 50];
        float m = row[0];
        for (int ki = 1; ki < 49; ki++) m = fmaxf(m, row[ki]);
        float sum = 0.f;
        for (int ki = 0; ki < 49; ki++) {
            float e = __expf(row[ki] - m);
            row[ki] = e;
            sum += e;
        }
        float inv = 1.f / sum;
        for (int ki = 0; ki < 49; ki++) row[ki] *= inv;
    }
    __syncthreads();

    // ---- O = relu(attn @ V): 784 tasks = 98 lp x 8 channel-groups of 8 ----
    unsigned short* Ou = (unsigned short*)O;
    for (int idx = tid; idx < 784; idx += 256) {
        int lp = idx >> 3, g = idx & 7;
        int r = lp / 14, c = lp % 14;
        int w = c / 7, cc = c - w * 7;
        int qi = r * 7 + cc;
        const float* srow = &sL[(w * 49 + qi) * 50];
        float a[8] = {0.f, 0.f, 0.f, 0.f, 0.f, 0.f, 0.f, 0.f};
#pragma unroll
        for (int ki = 0; ki < 49; ki++) {
            int lpk = (ki / 7) * 14 + w * 7 + ki % 7;
            union { uint4 q; unsigned short h[8]; } v8;
            v8.q = *(const uint4*)&vL[lpk * 64 + g * 8];
            float sv = srow[ki];
#pragma unroll
            for (int j = 0; j < 8; j++) a[j] += sv * bits2f(v8.h[j]);
        }
        int p = pbase + r * 28 + c;
        union { uint4 q; unsigned short h[8]; } o8;
#pragma unroll
        for (int j = 0; j < 8; j++) o8.h[j] = f2bits(fmaxf(a[j], 0.f));
        *(uint4*)&Ou[((size_t)n * PP + p) * 256 + hh * 64 + g * 8] = o8.q;
    }
}

// ---------------------------------------------------------------------------
extern "C" void kernel_launch(void* const* d_in, const int* in_sizes, int n_in,
                              void* d_out, int out_size, void* d_ws, size_t ws_size,
                              hipStream_t stream)
{
    const float* x0     = (const float*)d_in[0];
    const float* dw0_w  = (const float*)d_in[1];
    const float* dw0_s  = (const float*)d_in[2];
    const float* dw0_b  = (const float*)d_in[3];
    const float* dw1_w  = (const float*)d_in[4];
    const float* dw1_s  = (const float*)d_in[5];
    const float* dw1_b  = (const float*)d_in[6];
    const float* f0w1   = (const float*)d_in[7];
    const float* f0s1   = (const float*)d_in[8];
    const float* f0b1   = (const float*)d_in[9];
    const float* f0w2   = (const float*)d_in[10];
    const float* f0s2   = (const float*)d_in[11];
    const float* f0b2   = (const float*)d_in[12];
    const float* f1w1   = (const float*)d_in[13];
    const float* f1s1   = (const float*)d_in[14];
    const float* f1b1   = (const float*)d_in[15];
    const float* f1w2   = (const float*)d_in[16];
    const float* f1s2   = (const float*)d_in[17];
    const float* f1b2   = (const float*)d_in[18];
    const float* qkv_w  = (const float*)d_in[19];
    const float* qkv_s  = (const float*)d_in[20];
    const float* qkv_b  = (const float*)d_in[21];
    const float* dws_w  = (const float*)d_in[22];
    const float* dws_s  = (const float*)d_in[23];
    const float* dws_b  = (const float*)d_in[24];
    const float* proj_w = (const float*)d_in[25];
    const float* proj_s = (const float*)d_in[26];
    const float* proj_b = (const float*)d_in[27];
    const float* pos    = (const float*)d_in[28];

    // -------- workspace (aliased, same proven r8 scheme) --------
    const size_t NXB = (size_t)BB * DIMC * PP * 4;    // 51,380,224 B
    char* base  = (char*)d_ws;
    float* X1   = (float*)base;
    bf16*  Hb   = (bf16*)(base + NXB);
    bf16*  Qb   = Hb;                                  // alias, disjoint in time
    char*  C_   = base + 2 * NXB;
    bf16*  QKVb = (bf16*)C_;
    float* X2   = (float*)C_;                          // alias, disjoint in time
    bf16*  X1b  = (bf16*)(base + 3 * NXB);             // 25.7 MB
    bf16*  Wc   = (bf16*)(base + 3 * NXB + NXB / 2);
    bf16*  Ob   = (bf16*)d_out;
    float* outp = (float*)d_out;

    bf16* Wf0w1 = Wc;                  // [512][256]
    bf16* Wf0w2 = Wf0w1 + 131072;      // [256][512]
    bf16* Wf1w1 = Wf0w2 + 131072;      // [512][256]
    bf16* Wf1w2 = Wf1w1 + 131072;      // [256][512]
    bf16* Wqkv  = Wf1w2 + 131072;      // [384][256]
    bf16* Wproj = Wqkv + 98304;        // [256][256]

    dim3 blk(256);

    // 0) weights fp32 -> bf16
    cvt_f2b<<<512, blk, 0, stream>>>(f0w1, Wf0w1, 131072);
    cvt_f2b<<<512, blk, 0, stream>>>(f0w2, Wf0w2, 131072);
    cvt_f2b<<<512, blk, 0, stream>>>(f1w1, Wf1w1, 131072);
    cvt_f2b<<<512, blk, 0, stream>>>(f1w2, Wf1w2, 131072);
    cvt_f2b<<<384, blk, 0, stream>>>(qkv_w, Wqkv, 98304);
    cvt_f2b<<<256, blk, 0, stream>>>(proj_w, Wproj, 65536);

    // 1) x = x + dw0(x); mirror to NHWC bf16
    dw3x3_kernel<<<BB * DIMC, blk, 0, stream>>>(x0, dw0_w, dw0_s, dw0_b, X1);
    tr_cvt<<<dim3(25, 8, BB), blk, 0, stream>>>(X1, X1b);

    // 2-3) ffn0 (second GEMM refreshes both X1 fp32 and X1b NHWC)
    gemm_mfma<true, false, 0><<<dim3(7, HIDC / 64, BB), blk, 0, stream>>>(
        Wf0w1, X1b, f0s1, f0b1, nullptr, nullptr, Hb, HIDC, DIMC);
    gemm_mfma<false, true, 2><<<dim3(7, DIMC / 64, BB), blk, 0, stream>>>(
        Wf0w2, Hb, f0s2, f0b2, X1, X1, X1b, DIMC, HIDC);

    // 4-7) attention
    gemm_mfma<false, false, 0><<<dim3(7, 384 / 64, BB), blk, 0, stream>>>(
        Wqkv, X1b, qkv_s, qkv_b, nullptr, nullptr, QKVb, 384, DIMC);
    dws5x5_nhwc<<<dim3(196, BB), blk, 0, stream>>>(QKVb, dws_w, dws_s, dws_b, Qb);
    attn_kernel<<<dim3(8, NHH, BB), blk, 0, stream>>>(Qb, QKVb, pos, Ob);
    gemm_mfma<false, true, 1><<<dim3(7, DIMC / 64, BB), blk, 0, stream>>>(
        Wproj, Ob, proj_s, proj_b, X1, X1, nullptr, DIMC, DIMC);

    // 8) x = x + dw1(x)  (QKVb dead -> X2); mirror to NHWC bf16 (reuse X1b)
    dw3x3_kernel<<<BB * DIMC, blk, 0, stream>>>(X1, dw1_w, dw1_s, dw1_b, X2);
    tr_cvt<<<dim3(25, 8, BB), blk, 0, stream>>>(X2, X1b);

    // 9-10) ffn1, final fp32 NCHW to d_out
    gemm_mfma<true, false, 0><<<dim3(7, HIDC / 64, BB), blk, 0, stream>>>(
        Wf1w1, X1b, f1s1, f1b1, nullptr, nullptr, Hb, HIDC, DIMC);
    gemm_mfma<false, true, 1><<<dim3(7, DIMC / 64, BB), blk, 0, stream>>>(
        Wf1w2, Hb, f1s2, f1b2, X2, outp, nullptr, DIMC, HIDC);
}